// Round 1
// baseline (2313.309 us; speedup 1.0000x reference)
//
#include <hip/hip_runtime.h>
#include <cstdint>
#include <cmath>

#define NTOK 197
#define NHEAD 12
#define HD 64
#define CDIM 768

// ---------------------------------------------------------------------------
// Pre-gather relative-position bias: bias_pre[h][n][m] = table[relidx[n,m]*12+h]
// ---------------------------------------------------------------------------
__global__ __launch_bounds__(256) void bias_pre_kernel(
    const float* __restrict__ table, const int* __restrict__ relidx,
    float* __restrict__ bias_pre, int total)
{
  int i = blockIdx.x * 256 + threadIdx.x;
  if (i >= total) return;
  int nm = i % (NTOK * NTOK);
  int h  = i / (NTOK * NTOK);
  bias_pre[i] = table[relidx[nm] * NHEAD + h];
}

// ---------------------------------------------------------------------------
// fp32 GEMM: C[M,N] = A[M,K] @ B[N,K]^T (+ bias[n]), all row-major.
// 128x128 tile, BK=16, 256 threads, 8x8 micro-tile per thread.
// Only M may be non-multiple of 128 (guards on A loads / C stores).
// ---------------------------------------------------------------------------
__global__ __launch_bounds__(256) void sgemm_nt(
    const float* __restrict__ A, const float* __restrict__ B,
    const float* __restrict__ bias, float* __restrict__ C,
    int M, int N, int K)
{
  __shared__ float As[16][128];
  __shared__ float Bs[16][128];
  const int bm = blockIdx.y * 128;
  const int bn = blockIdx.x * 128;
  const int tid = threadIdx.x;
  const int lr = tid >> 2;          // 0..63 loader row
  const int lk = (tid & 3) << 2;    // 0,4,8,12 loader k
  const int tx = tid & 15;
  const int ty = tid >> 4;

  float acc[8][8];
#pragma unroll
  for (int i = 0; i < 8; ++i)
#pragma unroll
    for (int j = 0; j < 8; ++j) acc[i][j] = 0.0f;

  for (int k0 = 0; k0 < K; k0 += 16) {
    const int ra0 = bm + lr;
    const int ra1 = bm + lr + 64;
    float4 a0 = make_float4(0.f, 0.f, 0.f, 0.f);
    float4 a1 = make_float4(0.f, 0.f, 0.f, 0.f);
    if (ra0 < M) a0 = *(const float4*)(A + (size_t)ra0 * K + k0 + lk);
    if (ra1 < M) a1 = *(const float4*)(A + (size_t)ra1 * K + k0 + lk);
    const float4 b0 = *(const float4*)(B + (size_t)(bn + lr) * K + k0 + lk);
    const float4 b1 = *(const float4*)(B + (size_t)(bn + lr + 64) * K + k0 + lk);
    __syncthreads();
    As[lk + 0][lr] = a0.x; As[lk + 1][lr] = a0.y; As[lk + 2][lr] = a0.z; As[lk + 3][lr] = a0.w;
    As[lk + 0][lr + 64] = a1.x; As[lk + 1][lr + 64] = a1.y; As[lk + 2][lr + 64] = a1.z; As[lk + 3][lr + 64] = a1.w;
    Bs[lk + 0][lr] = b0.x; Bs[lk + 1][lr] = b0.y; Bs[lk + 2][lr] = b0.z; Bs[lk + 3][lr] = b0.w;
    Bs[lk + 0][lr + 64] = b1.x; Bs[lk + 1][lr + 64] = b1.y; Bs[lk + 2][lr + 64] = b1.z; Bs[lk + 3][lr + 64] = b1.w;
    __syncthreads();
#pragma unroll
    for (int kk = 0; kk < 16; ++kk) {
      const float4 av0 = *(const float4*)&As[kk][ty << 2];
      const float4 av1 = *(const float4*)&As[kk][64 + (ty << 2)];
      const float4 bv0 = *(const float4*)&Bs[kk][tx << 2];
      const float4 bv1 = *(const float4*)&Bs[kk][64 + (tx << 2)];
      const float ar[8] = {av0.x, av0.y, av0.z, av0.w, av1.x, av1.y, av1.z, av1.w};
      const float br[8] = {bv0.x, bv0.y, bv0.z, bv0.w, bv1.x, bv1.y, bv1.z, bv1.w};
#pragma unroll
      for (int i = 0; i < 8; ++i)
#pragma unroll
        for (int j = 0; j < 8; ++j)
          acc[i][j] = fmaf(ar[i], br[j], acc[i][j]);
    }
  }

  float bv[8] = {0.f, 0.f, 0.f, 0.f, 0.f, 0.f, 0.f, 0.f};
  if (bias) {
    const float4 x0 = *(const float4*)(bias + bn + (tx << 2));
    const float4 x1 = *(const float4*)(bias + bn + 64 + (tx << 2));
    bv[0] = x0.x; bv[1] = x0.y; bv[2] = x0.z; bv[3] = x0.w;
    bv[4] = x1.x; bv[5] = x1.y; bv[6] = x1.z; bv[7] = x1.w;
  }
#pragma unroll
  for (int i = 0; i < 8; ++i) {
    const int row = bm + ((i < 4) ? ((ty << 2) + i) : (64 + (ty << 2) + (i - 4)));
    if (row < M) {
      float4 o0 = make_float4(acc[i][0] + bv[0], acc[i][1] + bv[1],
                              acc[i][2] + bv[2], acc[i][3] + bv[3]);
      float4 o1 = make_float4(acc[i][4] + bv[4], acc[i][5] + bv[5],
                              acc[i][6] + bv[6], acc[i][7] + bv[7]);
      *(float4*)(C + (size_t)row * N + bn + (tx << 2)) = o0;
      *(float4*)(C + (size_t)row * N + bn + 64 + (tx << 2)) = o1;
    }
  }
}

// ---------------------------------------------------------------------------
// Fused binary attention per (b,h). 256 threads = 4 waves.
// qkv row layout per (b,n): [3][12][64] floats -> q at h*64, k at 768+h*64,
// v at 1536+h*64.
// Step 1: scales (mean|q|, mean|k|), k sign bits -> LDS, quantize_v -> LDS.
// Step 2: each wave owns 4 rows per group of 16; popcount logits + bias,
// wave-parallel softmax, quantize_p -> LDS, then PV with p-broadcast b128.
// ---------------------------------------------------------------------------
__global__ __launch_bounds__(256) void attn_kernel(
    const float* __restrict__ qkv, const float* __restrict__ bias_pre,
    float* __restrict__ att)
{
  __shared__ float v_lds[NTOK][HD];              // 50432 B
  __shared__ float p_lds[4][4][200];             // 12800 B (stride 200 for b128 align)
  __shared__ unsigned long long kb[NTOK];        // 1576 B
  __shared__ float red[8];                       // 32 B   (total 64840 B)

  const int bh = blockIdx.x;
  const int b = bh / NHEAD;
  const int h = bh % NHEAD;
  const int tid = threadIdx.x;
  const int w = tid >> 6;
  const int lane = tid & 63;
  const float* base = qkv + (size_t)b * (NTOK * 3 * CDIM) + h * HD;

  // ---- Step 1: scales, k sign bits, quantized v ----
  float sq = 0.f, sk = 0.f;
  for (int n = w; n < NTOK; n += 4) {
    const float* row = base + (size_t)n * (3 * CDIM);
    const float qv = row[lane];
    const float kv = row[CDIM + lane];
    const float vv = row[2 * CDIM + lane];
    sq += fabsf(qv);
    sk += fabsf(kv);
    const unsigned long long km = __ballot(kv >= 0.0f);
    if (lane == 0) kb[n] = km;
    const float c = fminf(fmaxf(vv, -2.0f), 2.0f);
    float a = fabsf(c);
#pragma unroll
    for (int off = 32; off; off >>= 1) a = fmaxf(a, __shfl_xor(a, off));
    const float s = 127.0f / (a + 1e-8f);
    v_lds[n][lane] = rintf(c * s) / s;
  }
#pragma unroll
  for (int off = 32; off; off >>= 1) {
    sq += __shfl_xor(sq, off);
    sk += __shfl_xor(sk, off);
  }
  if (lane == 0) { red[w] = sq; red[4 + w] = sk; }
  __syncthreads();
  const float s_q = (red[0] + red[1] + red[2] + red[3]) * (1.0f / (NTOK * HD));
  const float s_k = (red[4] + red[5] + red[6] + red[7]) * (1.0f / (NTOK * HD));
  const float coef = s_q * s_k * 0.125f;  // SCALE = 64^-0.5

  float* outb = att + (size_t)b * (NTOK * CDIM) + h * HD;
  const float* biash = bias_pre + (size_t)h * (NTOK * NTOK);
  const float SP = 1.0f / 255.0f;

  // ---- Step 2: per-wave groups of 4 rows ----
  for (int g = 0; g < 13; ++g) {
    const int r0 = g * 16 + w * 4;
    const int nr = (NTOK - r0 < 4) ? (NTOK - r0) : 4;
    if (nr <= 0) continue;  // uniform within wave

    // softmax + quantize_p for rows r0..r0+nr-1
#pragma unroll
    for (int i = 0; i < 4; ++i) {
      if (i < nr) {
        const int r = r0 + i;
        const float qvrow = base[(size_t)r * (3 * CDIM) + lane];
        const unsigned long long qn = __ballot(qvrow >= 0.0f);
        float lg[4];
#pragma unroll
        for (int t = 0; t < 4; ++t) {
          const int m = lane + t * 64;
          if (m < NTOK) {
            const int dot = 64 - 2 * __popcll(qn ^ kb[m]);
            lg[t] = fmaf(coef, (float)dot, biash[(size_t)r * NTOK + m]);
          } else {
            lg[t] = -INFINITY;
          }
        }
        float mx = fmaxf(fmaxf(lg[0], lg[1]), fmaxf(lg[2], lg[3]));
#pragma unroll
        for (int off = 32; off; off >>= 1) mx = fmaxf(mx, __shfl_xor(mx, off));
        const float p0 = expf(lg[0] - mx);
        const float p1 = expf(lg[1] - mx);
        const float p2 = expf(lg[2] - mx);
        const float p3 = expf(lg[3] - mx);
        float sum = p0 + p1 + p2 + p3;
#pragma unroll
        for (int off = 32; off; off >>= 1) sum += __shfl_xor(sum, off);
        // quantize_p: q = clip(rint((p/sum)/S), 0, 255); p = S*q
        float z0 = rintf((p0 / sum) / SP); z0 = fminf(fmaxf(z0, 0.f), 255.f);
        float z1 = rintf((p1 / sum) / SP); z1 = fminf(fmaxf(z1, 0.f), 255.f);
        float z2 = rintf((p2 / sum) / SP); z2 = fminf(fmaxf(z2, 0.f), 255.f);
        float z3 = rintf((p3 / sum) / SP); z3 = fminf(fmaxf(z3, 0.f), 255.f);
        p_lds[w][i][lane] = SP * z0;
        p_lds[w][i][lane + 64] = SP * z1;
        p_lds[w][i][lane + 128] = SP * z2;
        if (lane + 192 < NTOK) p_lds[w][i][lane + 192] = SP * z3;
      }
    }

    // PV: out[r][d=lane] = sum_m p[r][m] * v[m][d]
    float acc0[4] = {0.f, 0.f, 0.f, 0.f};
    for (int mc = 0; mc < 196; mc += 4) {
      float vv0 = v_lds[mc + 0][lane];
      float vv1 = v_lds[mc + 1][lane];
      float vv2 = v_lds[mc + 2][lane];
      float vv3 = v_lds[mc + 3][lane];
#pragma unroll
      for (int i = 0; i < 4; ++i) {
        if (i < nr) {
          const float4 pr = *(const float4*)&p_lds[w][i][mc];
          acc0[i] = fmaf(pr.x, vv0, acc0[i]);
          acc0[i] = fmaf(pr.y, vv1, acc0[i]);
          acc0[i] = fmaf(pr.z, vv2, acc0[i]);
          acc0[i] = fmaf(pr.w, vv3, acc0[i]);
        }
      }
    }
    {  // tail m = 196
      const float v196 = v_lds[196][lane];
#pragma unroll
      for (int i = 0; i < 4; ++i)
        if (i < nr) acc0[i] = fmaf(p_lds[w][i][196], v196, acc0[i]);
    }
#pragma unroll
    for (int i = 0; i < 4; ++i)
      if (i < nr) outb[(size_t)(r0 + i) * CDIM + lane] = acc0[i];
  }
}

// ---------------------------------------------------------------------------
extern "C" void kernel_launch(void* const* d_in, const int* in_sizes, int n_in,
                              void* d_out, int out_size, void* d_ws, size_t ws_size,
                              hipStream_t stream)
{
  (void)in_sizes; (void)n_in; (void)out_size;
  const float* x      = (const float*)d_in[0];
  const float* qkv_w  = (const float*)d_in[1];
  const float* proj_w = (const float*)d_in[2];
  const float* proj_b = (const float*)d_in[3];
  const float* table  = (const float*)d_in[4];
  const int*   relidx = (const int*)d_in[5];
  float* out = (float*)d_out;

  const size_t bias_elems = (size_t)NHEAD * NTOK * NTOK;  // 465,708 (16B aligned)

  // pick batch-chunk size so ws fits: bias + qkv chunk + att chunk
  int nb = 128;
  while (nb > 1) {
    const size_t need = (bias_elems +
                         (size_t)nb * NTOK * (3 * CDIM) +
                         (size_t)nb * NTOK * CDIM) * sizeof(float);
    if (need <= ws_size) break;
    nb >>= 1;
  }

  float* bias_pre = (float*)d_ws;
  float* qkvbuf = bias_pre + bias_elems;
  float* attbuf = qkvbuf + (size_t)nb * NTOK * (3 * CDIM);

  {
    const int total = (int)bias_elems;
    bias_pre_kernel<<<(total + 255) / 256, 256, 0, stream>>>(table, relidx, bias_pre, total);
  }

  for (int b0 = 0; b0 < 128; b0 += nb) {
    const int M = nb * NTOK;
    sgemm_nt<<<dim3((3 * CDIM) / 128, (M + 127) / 128), 256, 0, stream>>>(
        x + (size_t)b0 * NTOK * CDIM, qkv_w, nullptr, qkvbuf, M, 3 * CDIM, CDIM);
    attn_kernel<<<nb * NHEAD, 256, 0, stream>>>(qkvbuf, bias_pre, attbuf);
    sgemm_nt<<<dim3(CDIM / 128, (M + 127) / 128), 256, 0, stream>>>(
        attbuf, proj_w, proj_b, out + (size_t)b0 * NTOK * CDIM, M, CDIM, CDIM);
  }
}

// Round 2
// 2251.823 us; speedup vs baseline: 1.0273x; 1.0273x over previous
//
#include <hip/hip_runtime.h>
#include <cstdint>
#include <cmath>

#define NTOK 197
#define NHEAD 12
#define HD 64
#define CDIM 768

typedef __attribute__((ext_vector_type(8))) short short8v;   // 8 bf16
typedef __attribute__((ext_vector_type(4))) float f32x4;

__device__ __forceinline__ unsigned short f2bf(float f) {
  unsigned u = __builtin_bit_cast(unsigned, f);
  unsigned r = (u + 0x7fffu + ((u >> 16) & 1u)) >> 16;   // round-nearest-even
  return (unsigned short)r;
}
__device__ __forceinline__ float bf2f(unsigned short h) {
  unsigned u = ((unsigned)h) << 16;
  return __builtin_bit_cast(float, u);
}

__device__ __forceinline__ void gload_lds16(const unsigned short* g, unsigned short* l) {
  __builtin_amdgcn_global_load_lds(
      (const __attribute__((address_space(1))) unsigned int*)(const void*)g,
      (__attribute__((address_space(3))) unsigned int*)(void*)l, 16, 0, 0);
}

// ---------------------------------------------------------------------------
// bias_pre[h][n][m] = table[relidx[n,m]*12+h]
// ---------------------------------------------------------------------------
__global__ __launch_bounds__(256) void bias_pre_kernel(
    const float* __restrict__ table, const int* __restrict__ relidx,
    float* __restrict__ bias_pre, int total)
{
  int i = blockIdx.x * 256 + threadIdx.x;
  if (i >= total) return;
  int nm = i % (NTOK * NTOK);
  int h  = i / (NTOK * NTOK);
  bias_pre[i] = table[relidx[nm] * NHEAD + h];
}

// ---------------------------------------------------------------------------
// Split fp32 [Mreal x C] into 3 bf16 limb planes [Mpad x C] (pad rows = 0).
// x = limb0 + limb1 + limb2 with limb_i = bf16 of successive residuals.
// ---------------------------------------------------------------------------
__global__ __launch_bounds__(256) void split3_kernel(
    const float* __restrict__ src,
    unsigned short* __restrict__ d0, unsigned short* __restrict__ d1,
    unsigned short* __restrict__ d2,
    int Mreal, int C, long long total4)
{
  long long idx = (long long)blockIdx.x * 256 + threadIdx.x;
  if (idx >= total4) return;
  long long e = idx * 4;
  int r = (int)(e / C);
  float4 v = make_float4(0.f, 0.f, 0.f, 0.f);
  if (r < Mreal) v = *(const float4*)(src + e);
  const float vv[4] = {v.x, v.y, v.z, v.w};
  ushort4 o0, o1, o2;
  unsigned short* p0 = (unsigned short*)&o0;
  unsigned short* p1 = (unsigned short*)&o1;
  unsigned short* p2 = (unsigned short*)&o2;
#pragma unroll
  for (int i = 0; i < 4; ++i) {
    float x = vv[i];
    unsigned short h0 = f2bf(x);
    float r1 = x - bf2f(h0);
    unsigned short h1 = f2bf(r1);
    float r2 = r1 - bf2f(h1);
    unsigned short h2 = f2bf(r2);
    p0[i] = h0; p1[i] = h1; p2[i] = h2;
  }
  *(ushort4*)(d0 + e) = o0;
  *(ushort4*)(d1 + e) = o1;
  *(ushort4*)(d2 + e) = o2;
}

// ---------------------------------------------------------------------------
// Split-bf16 MFMA GEMM: C[M,N](f32) = sum_seg Aplane[ta][Mpad,K] @ Bplane[tb][N,K]^T
// segs: packed bytes (ta<<4)|tb. 128x128 tile, BK=32, 4 waves (2x2 of 64x64).
// ---------------------------------------------------------------------------
__global__ __launch_bounds__(256) void gemm_split_bf16(
    const unsigned short* __restrict__ A, size_t aplane,
    const unsigned short* __restrict__ B, size_t bplane,
    unsigned long long segs, int nseg,
    const float* __restrict__ bias, float* __restrict__ C,
    int M, int N, int K)
{
  __shared__ unsigned short Asm[128][32];
  __shared__ unsigned short Bsm[128][32];
  const int tid = threadIdx.x;
  const int w = tid >> 6;
  const int lane = tid & 63;
  const int bm = blockIdx.y * 128;
  const int bn = blockIdx.x * 128;
  const int sr = tid >> 2;          // staging row 0..63
  const int sc = (tid & 3) * 8;     // staging col (shorts)

  f32x4 acc[4][4];
#pragma unroll
  for (int i = 0; i < 4; ++i)
#pragma unroll
    for (int j = 0; j < 4; ++j) acc[i][j] = (f32x4){0.f, 0.f, 0.f, 0.f};

  const int mrow = (w >> 1) * 64 + (lane & 15);
  const int nrow = (w & 1) * 64 + (lane & 15);
  const int kc = 8 * (lane >> 4);

  for (int s = 0; s < nseg; ++s) {
    const unsigned int sb = (unsigned int)((segs >> (8 * s)) & 0xFFu);
    const unsigned short* Ap = A + (size_t)(sb >> 4) * aplane;
    const unsigned short* Bp = B + (size_t)(sb & 0xF) * bplane;
#pragma unroll 1
    for (int k0 = 0; k0 < K; k0 += 32) {
      gload_lds16(Ap + (size_t)(bm + sr) * K + k0 + sc, &Asm[sr][sc]);
      gload_lds16(Ap + (size_t)(bm + sr + 64) * K + k0 + sc, &Asm[sr + 64][sc]);
      gload_lds16(Bp + (size_t)(bn + sr) * K + k0 + sc, &Bsm[sr][sc]);
      gload_lds16(Bp + (size_t)(bn + sr + 64) * K + k0 + sc, &Bsm[sr + 64][sc]);
      __syncthreads();
      short8v av[4], bv[4];
#pragma unroll
      for (int mt = 0; mt < 4; ++mt)
        av[mt] = *(const short8v*)&Asm[mrow + mt * 16][kc];
#pragma unroll
      for (int nt = 0; nt < 4; ++nt)
        bv[nt] = *(const short8v*)&Bsm[nrow + nt * 16][kc];
#pragma unroll
      for (int mt = 0; mt < 4; ++mt)
#pragma unroll
        for (int nt = 0; nt < 4; ++nt)
          acc[mt][nt] = __builtin_amdgcn_mfma_f32_16x16x32_bf16(
              av[mt], bv[nt], acc[mt][nt], 0, 0, 0);
      __syncthreads();
    }
  }

  // epilogue: C/D layout col = lane&15, row = (lane>>4)*4 + j
#pragma unroll
  for (int nt = 0; nt < 4; ++nt) {
    const int col = bn + (w & 1) * 64 + nt * 16 + (lane & 15);
    const float bcol = bias ? bias[col] : 0.0f;
#pragma unroll
    for (int mt = 0; mt < 4; ++mt) {
      const int rowbase = bm + (w >> 1) * 64 + mt * 16 + ((lane >> 4) << 2);
#pragma unroll
      for (int j = 0; j < 4; ++j) {
        const int row = rowbase + j;
        if (row < M) C[(size_t)row * N + col] = acc[mt][nt][j] + bcol;
      }
    }
  }
}

// ---------------------------------------------------------------------------
// Fused binary attention per (b,h); writes output as 2 bf16 limb planes.
// ---------------------------------------------------------------------------
__global__ __launch_bounds__(256) void attn_kernel(
    const float* __restrict__ qkv, const float* __restrict__ bias_pre,
    unsigned short* __restrict__ att0, unsigned short* __restrict__ att1)
{
  __shared__ float v_lds[NTOK][HD];
  __shared__ float p_lds[4][4][200];
  __shared__ unsigned long long kb[NTOK];
  __shared__ float red[8];

  const int bh = blockIdx.x;
  const int b = bh / NHEAD;
  const int h = bh % NHEAD;
  const int tid = threadIdx.x;
  const int w = tid >> 6;
  const int lane = tid & 63;
  const float* base = qkv + (size_t)b * (NTOK * 3 * CDIM) + h * HD;

  float sq = 0.f, sk = 0.f;
  for (int n = w; n < NTOK; n += 4) {
    const float* row = base + (size_t)n * (3 * CDIM);
    const float qv = row[lane];
    const float kv = row[CDIM + lane];
    const float vv = row[2 * CDIM + lane];
    sq += fabsf(qv);
    sk += fabsf(kv);
    const unsigned long long km = __ballot(kv >= 0.0f);
    if (lane == 0) kb[n] = km;
    const float c = fminf(fmaxf(vv, -2.0f), 2.0f);
    float a = fabsf(c);
#pragma unroll
    for (int off = 32; off; off >>= 1) a = fmaxf(a, __shfl_xor(a, off));
    const float s = 127.0f / (a + 1e-8f);
    v_lds[n][lane] = rintf(c * s) / s;
  }
#pragma unroll
  for (int off = 32; off; off >>= 1) {
    sq += __shfl_xor(sq, off);
    sk += __shfl_xor(sk, off);
  }
  if (lane == 0) { red[w] = sq; red[4 + w] = sk; }
  __syncthreads();
  const float s_q = (red[0] + red[1] + red[2] + red[3]) * (1.0f / (NTOK * HD));
  const float s_k = (red[4] + red[5] + red[6] + red[7]) * (1.0f / (NTOK * HD));
  const float coef = s_q * s_k * 0.125f;

  const float* biash = bias_pre + (size_t)h * (NTOK * NTOK);
  const float SP = 1.0f / 255.0f;

  for (int g = 0; g < 13; ++g) {
    const int r0 = g * 16 + w * 4;
    const int nr = (NTOK - r0 < 4) ? (NTOK - r0) : 4;
    if (nr <= 0) continue;

#pragma unroll
    for (int i = 0; i < 4; ++i) {
      if (i < nr) {
        const int r = r0 + i;
        const float qvrow = base[(size_t)r * (3 * CDIM) + lane];
        const unsigned long long qn = __ballot(qvrow >= 0.0f);
        float lg[4];
#pragma unroll
        for (int t = 0; t < 4; ++t) {
          const int m = lane + t * 64;
          if (m < NTOK) {
            const int dot = 64 - 2 * __popcll(qn ^ kb[m]);
            lg[t] = fmaf(coef, (float)dot, biash[(size_t)r * NTOK + m]);
          } else {
            lg[t] = -INFINITY;
          }
        }
        float mx = fmaxf(fmaxf(lg[0], lg[1]), fmaxf(lg[2], lg[3]));
#pragma unroll
        for (int off = 32; off; off >>= 1) mx = fmaxf(mx, __shfl_xor(mx, off));
        const float p0 = expf(lg[0] - mx);
        const float p1 = expf(lg[1] - mx);
        const float p2 = expf(lg[2] - mx);
        const float p3 = expf(lg[3] - mx);
        float sum = p0 + p1 + p2 + p3;
#pragma unroll
        for (int off = 32; off; off >>= 1) sum += __shfl_xor(sum, off);
        float z0 = rintf((p0 / sum) / SP); z0 = fminf(fmaxf(z0, 0.f), 255.f);
        float z1 = rintf((p1 / sum) / SP); z1 = fminf(fmaxf(z1, 0.f), 255.f);
        float z2 = rintf((p2 / sum) / SP); z2 = fminf(fmaxf(z2, 0.f), 255.f);
        float z3 = rintf((p3 / sum) / SP); z3 = fminf(fmaxf(z3, 0.f), 255.f);
        p_lds[w][i][lane] = SP * z0;
        p_lds[w][i][lane + 64] = SP * z1;
        p_lds[w][i][lane + 128] = SP * z2;
        if (lane + 192 < NTOK) p_lds[w][i][lane + 192] = SP * z3;
      }
    }

    float acc0[4] = {0.f, 0.f, 0.f, 0.f};
    for (int mc = 0; mc < 196; mc += 4) {
      float vv0 = v_lds[mc + 0][lane];
      float vv1 = v_lds[mc + 1][lane];
      float vv2 = v_lds[mc + 2][lane];
      float vv3 = v_lds[mc + 3][lane];
#pragma unroll
      for (int i = 0; i < 4; ++i) {
        if (i < nr) {
          const float4 pr = *(const float4*)&p_lds[w][i][mc];
          acc0[i] = fmaf(pr.x, vv0, acc0[i]);
          acc0[i] = fmaf(pr.y, vv1, acc0[i]);
          acc0[i] = fmaf(pr.z, vv2, acc0[i]);
          acc0[i] = fmaf(pr.w, vv3, acc0[i]);
        }
      }
    }
    {
      const float v196 = v_lds[196][lane];
#pragma unroll
      for (int i = 0; i < 4; ++i)
        if (i < nr) acc0[i] = fmaf(p_lds[w][i][196], v196, acc0[i]);
    }
#pragma unroll
    for (int i = 0; i < 4; ++i)
      if (i < nr) {
        const size_t row = (size_t)b * NTOK + (r0 + i);
        const size_t off = row * CDIM + h * HD + lane;
        const float o = acc0[i];
        const unsigned short h0 = f2bf(o);
        const unsigned short h1 = f2bf(o - bf2f(h0));
        att0[off] = h0;
        att1[off] = h1;
      }
  }
}

// ---------------------------------------------------------------------------
extern "C" void kernel_launch(void* const* d_in, const int* in_sizes, int n_in,
                              void* d_out, int out_size, void* d_ws, size_t ws_size,
                              hipStream_t stream)
{
  (void)in_sizes; (void)n_in; (void)out_size;
  const float* x      = (const float*)d_in[0];
  const float* qkv_w  = (const float*)d_in[1];
  const float* proj_w = (const float*)d_in[2];
  const float* proj_b = (const float*)d_in[3];
  const float* table  = (const float*)d_in[4];
  const int*   relidx = (const int*)d_in[5];
  float* out = (float*)d_out;

  const size_t biasElems = (size_t)NHEAD * NTOK * NTOK;       // 465708 f32
  const size_t wqPlane = (size_t)(3 * CDIM) * CDIM;           // 2304*768 bf16
  const size_t wpPlane = (size_t)CDIM * CDIM;                 // 768*768  bf16

  // adaptive batch chunk
  int nb = 128;
  size_t Mpad = 0;
  for (;; nb >>= 1) {
    size_t Mreal = (size_t)nb * NTOK;
    Mpad = (Mreal + 127) & ~(size_t)127;
    size_t need = biasElems * 4 + (3 * wqPlane + 3 * wpPlane) * 2 +
                  3 * Mpad * CDIM * 2 +          // x/att split planes (bf16)
                  Mpad * (size_t)(3 * CDIM) * 4; // qkv buf (f32)
    if (need <= ws_size || nb == 1) break;
  }
  const size_t MrealFull = (size_t)nb * NTOK;

  char* p = (char*)d_ws;
  float* bias_pre = (float*)p;               p += biasElems * 4;
  unsigned short* wq = (unsigned short*)p;   p += 3 * wqPlane * 2;
  unsigned short* wp = (unsigned short*)p;   p += 3 * wpPlane * 2;
  unsigned short* xs = (unsigned short*)p;   p += 3 * Mpad * CDIM * 2;
  float* qkvbuf = (float*)p;

  const size_t xPlane = Mpad * CDIM;

  {
    const int total = (int)biasElems;
    bias_pre_kernel<<<(total + 255) / 256, 256, 0, stream>>>(table, relidx, bias_pre, total);
  }
  {  // weight splits (no padding needed: 2304,768 multiples of 128)
    long long t4 = (long long)(3 * CDIM) * CDIM / 4;
    split3_kernel<<<(int)((t4 + 255) / 256), 256, 0, stream>>>(
        qkv_w, wq, wq + wqPlane, wq + 2 * wqPlane, 3 * CDIM, CDIM, t4);
    t4 = (long long)CDIM * CDIM / 4;
    split3_kernel<<<(int)((t4 + 255) / 256), 256, 0, stream>>>(
        proj_w, wp, wp + wpPlane, wp + 2 * wpPlane, CDIM, CDIM, t4);
  }

  // segment lists: bytes (ta<<4)|tb
  const unsigned long long SEG_QKV = 0x200211100100ULL;  // {00,01,10,11,02,20}
  const unsigned long long SEG_PRJ = 0x100100ULL;        // {00,01,10}

  for (int b0 = 0; b0 < 128; b0 += nb) {
    const int curB = (128 - b0 < nb) ? (128 - b0) : nb;
    const int Mreal = curB * NTOK;
    (void)MrealFull;
    // 1) split x chunk into 3 bf16 planes (pad rows zeroed)
    {
      long long t4 = (long long)Mpad * CDIM / 4;
      split3_kernel<<<(int)((t4 + 255) / 256), 256, 0, stream>>>(
          x + (size_t)b0 * NTOK * CDIM, xs, xs + xPlane, xs + 2 * xPlane,
          Mreal, CDIM, t4);
    }
    // 2) qkv GEMM (6 segments)
    gemm_split_bf16<<<dim3((3 * CDIM) / 128, (int)(Mpad / 128)), 256, 0, stream>>>(
        xs, xPlane, wq, wqPlane, SEG_QKV, 6, nullptr, qkvbuf,
        Mreal, 3 * CDIM, CDIM);
    // 3) fused attention -> att limbs (reuse xs planes 0,1)
    attn_kernel<<<curB * NHEAD, 256, 0, stream>>>(qkvbuf, bias_pre, xs, xs + xPlane);
    // 4) proj GEMM (3 segments) + bias -> out
    gemm_split_bf16<<<dim3(CDIM / 128, (int)(Mpad / 128)), 256, 0, stream>>>(
        xs, xPlane, wp, wpPlane, SEG_PRJ, 3, proj_b, out + (size_t)b0 * NTOK * CDIM,
        Mreal, CDIM, CDIM);
  }
}

// Round 3
// 1767.539 us; speedup vs baseline: 1.3088x; 1.2740x over previous
//
#include <hip/hip_runtime.h>
#include <cstdint>
#include <cmath>

#define NTOK 197
#define NHEAD 12
#define HD 64
#define CDIM 768

typedef __attribute__((ext_vector_type(8))) short short8v;   // 8 bf16
typedef __attribute__((ext_vector_type(4))) float f32x4;

__device__ __forceinline__ unsigned short f2bf(float f) {
  unsigned u = __builtin_bit_cast(unsigned, f);
  unsigned r = (u + 0x7fffu + ((u >> 16) & 1u)) >> 16;   // round-nearest-even
  return (unsigned short)r;
}
__device__ __forceinline__ float bf2f(unsigned short h) {
  unsigned u = ((unsigned)h) << 16;
  return __builtin_bit_cast(float, u);
}

__device__ __forceinline__ void gload_lds16(const unsigned short* g, unsigned short* l) {
  __builtin_amdgcn_global_load_lds(
      (const __attribute__((address_space(1))) unsigned int*)(const void*)g,
      (__attribute__((address_space(3))) unsigned int*)(void*)l, 16, 0, 0);
}

// ---------------------------------------------------------------------------
// bias_pre[h][n][m] = table[relidx[n,m]*12+h]
// ---------------------------------------------------------------------------
__global__ __launch_bounds__(256) void bias_pre_kernel(
    const float* __restrict__ table, const int* __restrict__ relidx,
    float* __restrict__ bias_pre, int total)
{
  int i = blockIdx.x * 256 + threadIdx.x;
  if (i >= total) return;
  int nm = i % (NTOK * NTOK);
  int h  = i / (NTOK * NTOK);
  bias_pre[i] = table[relidx[nm] * NHEAD + h];
}

// ---------------------------------------------------------------------------
// Split fp32 [Mreal x C] into 3 bf16 limb planes [Mpad x C] (pad rows = 0).
// ---------------------------------------------------------------------------
__global__ __launch_bounds__(256) void split3_kernel(
    const float* __restrict__ src,
    unsigned short* __restrict__ d0, unsigned short* __restrict__ d1,
    unsigned short* __restrict__ d2,
    int Mreal, int C, long long total4)
{
  long long idx = (long long)blockIdx.x * 256 + threadIdx.x;
  if (idx >= total4) return;
  long long e = idx * 4;
  int r = (int)(e / C);
  float4 v = make_float4(0.f, 0.f, 0.f, 0.f);
  if (r < Mreal) v = *(const float4*)(src + e);
  const float vv[4] = {v.x, v.y, v.z, v.w};
  ushort4 o0, o1, o2;
  unsigned short* p0 = (unsigned short*)&o0;
  unsigned short* p1 = (unsigned short*)&o1;
  unsigned short* p2 = (unsigned short*)&o2;
#pragma unroll
  for (int i = 0; i < 4; ++i) {
    float x = vv[i];
    unsigned short h0 = f2bf(x);
    float r1 = x - bf2f(h0);
    unsigned short h1 = f2bf(r1);
    float r2 = r1 - bf2f(h1);
    unsigned short h2 = f2bf(r2);
    p0[i] = h0; p1[i] = h1; p2[i] = h2;
  }
  *(ushort4*)(d0 + e) = o0;
  *(ushort4*)(d1 + e) = o1;
  *(ushort4*)(d2 + e) = o2;
}

// ---------------------------------------------------------------------------
// Segment-fused split-bf16 MFMA GEMM.
// C[M,N](f32) = sum_seg A[ta][Mpad,K] @ B[tb][N,K]^T  (+bias)
// Per K-step: stage NA A-limb tiles + NB B-limb tiles (once), then run all
// NSEG MFMA passes between ONE barrier pair. 128x128 tile, BK=32, 4 waves.
// LDS granule XOR-swizzle g^=((row>>1)&3) applied at staging SOURCE (dest
// linear, per global_load_lds rules) and at fragment read.
// 1D grid with bijective XCD-chunk swizzle.
// ---------------------------------------------------------------------------
template <int NA, int NB, int NSEG, unsigned long long SEGS>
__global__ __launch_bounds__(256, 3) void gemm_fused(
    const unsigned short* __restrict__ A, size_t aplane,
    const unsigned short* __restrict__ B, size_t bplane,
    const float* __restrict__ bias, float* __restrict__ C,
    int M, int N, int K)
{
  __shared__ unsigned short sm[NA + NB][128][32];

  // bijective XCD-chunk block swizzle (m204)
  const int nwg = gridDim.x;
  const int orig = blockIdx.x;
  const int q = nwg >> 3, r = nwg & 7;
  const int xcd = orig & 7, pos = orig >> 3;
  const int wg = (xcd < r ? xcd * (q + 1) : r * (q + 1) + (xcd - r) * q) + pos;
  const int gridX = N >> 7;
  const int by = wg / gridX, bx = wg % gridX;
  const int bm = by * 128, bn = bx * 128;

  const int tid = threadIdx.x;
  const int w = tid >> 6, lane = tid & 63;
  const int sr = tid >> 2, gi = tid & 3;          // staging row / granule
  const int sgW = (gi ^ ((sr >> 1) & 3)) * 8;     // swizzled source col (shorts)
  const int scW = gi * 8;                         // linear LDS dest col
  const int mrow = (w >> 1) * 64 + (lane & 15);
  const int nrow = (w & 1) * 64 + (lane & 15);
  const int kcsw = 8 * ((lane >> 4) ^ (((lane & 15) >> 1) & 3));  // swizzled read col

  const size_t aoff0 = (size_t)(bm + sr) * K + sgW;
  const size_t aoff1 = (size_t)(bm + sr + 64) * K + sgW;
  const size_t boff0 = (size_t)(bn + sr) * K + sgW;
  const size_t boff1 = (size_t)(bn + sr + 64) * K + sgW;

  f32x4 acc[4][4];
#pragma unroll
  for (int i = 0; i < 4; ++i)
#pragma unroll
    for (int j = 0; j < 4; ++j) acc[i][j] = (f32x4){0.f, 0.f, 0.f, 0.f};

#pragma unroll 1
  for (int k0 = 0; k0 < K; k0 += 32) {
#pragma unroll
    for (int a = 0; a < NA; ++a) {
      const unsigned short* Ap = A + (size_t)a * aplane + k0;
      gload_lds16(Ap + aoff0, &sm[a][sr][scW]);
      gload_lds16(Ap + aoff1, &sm[a][sr + 64][scW]);
    }
#pragma unroll
    for (int b2 = 0; b2 < NB; ++b2) {
      const unsigned short* Bp = B + (size_t)b2 * bplane + k0;
      gload_lds16(Bp + boff0, &sm[NA + b2][sr][scW]);
      gload_lds16(Bp + boff1, &sm[NA + b2][sr + 64][scW]);
    }
    __syncthreads();
#pragma unroll
    for (int s = 0; s < NSEG; ++s) {
      constexpr unsigned long long SB = 0xFFULL;
      const int ta = (int)((SEGS >> (8 * s)) & SB) >> 4;
      const int tb = (int)((SEGS >> (8 * s)) & 0x0FULL);
      short8v av[4], bv[4];
#pragma unroll
      for (int mt = 0; mt < 4; ++mt)
        av[mt] = *(const short8v*)&sm[ta][mrow + mt * 16][kcsw];
#pragma unroll
      for (int nt = 0; nt < 4; ++nt)
        bv[nt] = *(const short8v*)&sm[NA + tb][nrow + nt * 16][kcsw];
#pragma unroll
      for (int mt = 0; mt < 4; ++mt)
#pragma unroll
        for (int nt = 0; nt < 4; ++nt)
          acc[mt][nt] = __builtin_amdgcn_mfma_f32_16x16x32_bf16(
              av[mt], bv[nt], acc[mt][nt], 0, 0, 0);
    }
    __syncthreads();
  }

  // epilogue: C/D layout col = lane&15, row = (lane>>4)*4 + j
#pragma unroll
  for (int nt = 0; nt < 4; ++nt) {
    const int col = bn + (w & 1) * 64 + nt * 16 + (lane & 15);
    const float bcol = bias ? bias[col] : 0.0f;
#pragma unroll
    for (int mt = 0; mt < 4; ++mt) {
      const int rowbase = bm + (w >> 1) * 64 + mt * 16 + ((lane >> 4) << 2);
#pragma unroll
      for (int j = 0; j < 4; ++j) {
        const int row = rowbase + j;
        if (row < M) C[(size_t)row * N + col] = acc[mt][nt][j] + bcol;
      }
    }
  }
}

// ---------------------------------------------------------------------------
// Fused binary attention per (b,h); writes output as 2 bf16 limb planes.
// ---------------------------------------------------------------------------
__global__ __launch_bounds__(256) void attn_kernel(
    const float* __restrict__ qkv, const float* __restrict__ bias_pre,
    unsigned short* __restrict__ att0, unsigned short* __restrict__ att1)
{
  __shared__ float v_lds[NTOK][HD];
  __shared__ float p_lds[4][4][200];
  __shared__ unsigned long long kb[NTOK];
  __shared__ float red[8];

  const int bh = blockIdx.x;
  const int b = bh / NHEAD;
  const int h = bh % NHEAD;
  const int tid = threadIdx.x;
  const int w = tid >> 6;
  const int lane = tid & 63;
  const float* base = qkv + (size_t)b * (NTOK * 3 * CDIM) + h * HD;

  float sq = 0.f, sk = 0.f;
  for (int n = w; n < NTOK; n += 4) {
    const float* row = base + (size_t)n * (3 * CDIM);
    const float qv = row[lane];
    const float kv = row[CDIM + lane];
    const float vv = row[2 * CDIM + lane];
    sq += fabsf(qv);
    sk += fabsf(kv);
    const unsigned long long km = __ballot(kv >= 0.0f);
    if (lane == 0) kb[n] = km;
    const float c = fminf(fmaxf(vv, -2.0f), 2.0f);
    float a = fabsf(c);
#pragma unroll
    for (int off = 32; off; off >>= 1) a = fmaxf(a, __shfl_xor(a, off));
    const float s = 127.0f / (a + 1e-8f);
    v_lds[n][lane] = rintf(c * s) / s;
  }
#pragma unroll
  for (int off = 32; off; off >>= 1) {
    sq += __shfl_xor(sq, off);
    sk += __shfl_xor(sk, off);
  }
  if (lane == 0) { red[w] = sq; red[4 + w] = sk; }
  __syncthreads();
  const float s_q = (red[0] + red[1] + red[2] + red[3]) * (1.0f / (NTOK * HD));
  const float s_k = (red[4] + red[5] + red[6] + red[7]) * (1.0f / (NTOK * HD));
  const float coef = s_q * s_k * 0.125f;

  const float* biash = bias_pre + (size_t)h * (NTOK * NTOK);
  const float SP = 1.0f / 255.0f;

  for (int g = 0; g < 13; ++g) {
    const int r0 = g * 16 + w * 4;
    const int nr = (NTOK - r0 < 4) ? (NTOK - r0) : 4;
    if (nr <= 0) continue;

#pragma unroll
    for (int i = 0; i < 4; ++i) {
      if (i < nr) {
        const int r = r0 + i;
        const float qvrow = base[(size_t)r * (3 * CDIM) + lane];
        const unsigned long long qn = __ballot(qvrow >= 0.0f);
        float lg[4];
#pragma unroll
        for (int t = 0; t < 4; ++t) {
          const int m = lane + t * 64;
          if (m < NTOK) {
            const int dot = 64 - 2 * __popcll(qn ^ kb[m]);
            lg[t] = fmaf(coef, (float)dot, biash[(size_t)r * NTOK + m]);
          } else {
            lg[t] = -INFINITY;
          }
        }
        float mx = fmaxf(fmaxf(lg[0], lg[1]), fmaxf(lg[2], lg[3]));
#pragma unroll
        for (int off = 32; off; off >>= 1) mx = fmaxf(mx, __shfl_xor(mx, off));
        const float p0 = expf(lg[0] - mx);
        const float p1 = expf(lg[1] - mx);
        const float p2 = expf(lg[2] - mx);
        const float p3 = expf(lg[3] - mx);
        float sum = p0 + p1 + p2 + p3;
#pragma unroll
        for (int off = 32; off; off >>= 1) sum += __shfl_xor(sum, off);
        float z0 = rintf((p0 / sum) / SP); z0 = fminf(fmaxf(z0, 0.f), 255.f);
        float z1 = rintf((p1 / sum) / SP); z1 = fminf(fmaxf(z1, 0.f), 255.f);
        float z2 = rintf((p2 / sum) / SP); z2 = fminf(fmaxf(z2, 0.f), 255.f);
        float z3 = rintf((p3 / sum) / SP); z3 = fminf(fmaxf(z3, 0.f), 255.f);
        p_lds[w][i][lane] = SP * z0;
        p_lds[w][i][lane + 64] = SP * z1;
        p_lds[w][i][lane + 128] = SP * z2;
        if (lane + 192 < NTOK) p_lds[w][i][lane + 192] = SP * z3;
      }
    }

    float acc0[4] = {0.f, 0.f, 0.f, 0.f};
    for (int mc = 0; mc < 196; mc += 4) {
      float vv0 = v_lds[mc + 0][lane];
      float vv1 = v_lds[mc + 1][lane];
      float vv2 = v_lds[mc + 2][lane];
      float vv3 = v_lds[mc + 3][lane];
#pragma unroll
      for (int i = 0; i < 4; ++i) {
        if (i < nr) {
          const float4 pr = *(const float4*)&p_lds[w][i][mc];
          acc0[i] = fmaf(pr.x, vv0, acc0[i]);
          acc0[i] = fmaf(pr.y, vv1, acc0[i]);
          acc0[i] = fmaf(pr.z, vv2, acc0[i]);
          acc0[i] = fmaf(pr.w, vv3, acc0[i]);
        }
      }
    }
    {
      const float v196 = v_lds[196][lane];
#pragma unroll
      for (int i = 0; i < 4; ++i)
        if (i < nr) acc0[i] = fmaf(p_lds[w][i][196], v196, acc0[i]);
    }
#pragma unroll
    for (int i = 0; i < 4; ++i)
      if (i < nr) {
        const size_t row = (size_t)b * NTOK + (r0 + i);
        const size_t off = row * CDIM + h * HD + lane;
        const float o = acc0[i];
        const unsigned short h0 = f2bf(o);
        const unsigned short h1 = f2bf(o - bf2f(h0));
        att0[off] = h0;
        att1[off] = h1;
      }
  }
}

// ---------------------------------------------------------------------------
extern "C" void kernel_launch(void* const* d_in, const int* in_sizes, int n_in,
                              void* d_out, int out_size, void* d_ws, size_t ws_size,
                              hipStream_t stream)
{
  (void)in_sizes; (void)n_in; (void)out_size;
  const float* x      = (const float*)d_in[0];
  const float* qkv_w  = (const float*)d_in[1];
  const float* proj_w = (const float*)d_in[2];
  const float* proj_b = (const float*)d_in[3];
  const float* table  = (const float*)d_in[4];
  const int*   relidx = (const int*)d_in[5];
  float* out = (float*)d_out;

  const size_t biasElems = (size_t)NHEAD * NTOK * NTOK;       // 465708 f32
  const size_t wqPlane = (size_t)(3 * CDIM) * CDIM;           // 2304*768 bf16
  const size_t wpPlane = (size_t)CDIM * CDIM;                 // 768*768  bf16

  // adaptive batch chunk
  int nb = 128;
  size_t Mpad = 0;
  for (;; nb >>= 1) {
    size_t Mreal = (size_t)nb * NTOK;
    Mpad = (Mreal + 127) & ~(size_t)127;
    size_t need = biasElems * 4 + (3 * wqPlane + 3 * wpPlane) * 2 +
                  3 * Mpad * CDIM * 2 +          // x/att split planes (bf16)
                  Mpad * (size_t)(3 * CDIM) * 4; // qkv buf (f32)
    if (need <= ws_size || nb == 1) break;
  }

  char* p = (char*)d_ws;
  float* bias_pre = (float*)p;               p += biasElems * 4;
  unsigned short* wq = (unsigned short*)p;   p += 3 * wqPlane * 2;
  unsigned short* wp = (unsigned short*)p;   p += 3 * wpPlane * 2;
  unsigned short* xs = (unsigned short*)p;   p += 3 * Mpad * CDIM * 2;
  float* qkvbuf = (float*)p;

  const size_t xPlane = Mpad * CDIM;

  {
    const int total = (int)biasElems;
    bias_pre_kernel<<<(total + 255) / 256, 256, 0, stream>>>(table, relidx, bias_pre, total);
  }
  {  // weight splits (2304 and 768 are multiples of 128: no padding)
    long long t4 = (long long)(3 * CDIM) * CDIM / 4;
    split3_kernel<<<(int)((t4 + 255) / 256), 256, 0, stream>>>(
        qkv_w, wq, wq + wqPlane, wq + 2 * wqPlane, 3 * CDIM, CDIM, t4);
    t4 = (long long)CDIM * CDIM / 4;
    split3_kernel<<<(int)((t4 + 255) / 256), 256, 0, stream>>>(
        proj_w, wp, wp + wpPlane, wp + 2 * wpPlane, CDIM, CDIM, t4);
  }

  // segments (ta<<4)|tb, ordered for A-plane reuse: {00,01,02,10,11,20}
  constexpr unsigned long long SEG_QKV = 0x201110020100ULL;
  constexpr unsigned long long SEG_PRJ = 0x100100ULL;        // {00,01,10}

  for (int b0 = 0; b0 < 128; b0 += nb) {
    const int curB = (128 - b0 < nb) ? (128 - b0) : nb;
    const int Mreal = curB * NTOK;
    // 1) split x chunk into 3 bf16 planes (pad rows zeroed)
    {
      long long t4 = (long long)Mpad * CDIM / 4;
      split3_kernel<<<(int)((t4 + 255) / 256), 256, 0, stream>>>(
          x + (size_t)b0 * NTOK * CDIM, xs, xs + xPlane, xs + 2 * xPlane,
          Mreal, CDIM, t4);
    }
    // 2) qkv GEMM (segment-fused)
    gemm_fused<3, 3, 6, SEG_QKV>
        <<<(int)(Mpad / 128) * ((3 * CDIM) / 128), 256, 0, stream>>>(
        xs, xPlane, wq, wqPlane, nullptr, qkvbuf, Mreal, 3 * CDIM, CDIM);
    // 3) fused attention -> att limbs (reuse xs planes 0,1; pads stay zero)
    attn_kernel<<<curB * NHEAD, 256, 0, stream>>>(qkvbuf, bias_pre, xs, xs + xPlane);
    // 4) proj GEMM (segment-fused) + bias -> out
    gemm_fused<2, 2, 3, SEG_PRJ>
        <<<(int)(Mpad / 128) * (CDIM / 128), 256, 0, stream>>>(
        xs, xPlane, wp, wpPlane, proj_b, out + (size_t)b0 * NTOK * CDIM,
        Mreal, CDIM, CDIM);
  }
}

// Round 4
// 1160.069 us; speedup vs baseline: 1.9941x; 1.5236x over previous
//
#include <hip/hip_runtime.h>
#include <cstdint>
#include <cmath>

#define NTOK 197
#define NHEAD 12
#define HD 64
#define CDIM 768
#define KPZ 200   // z-row stride (bytes, mult of 8)
#define KPV 200   // vT-row stride (shorts, mult of 8)

typedef __attribute__((ext_vector_type(8))) short short8v;   // 8 bf16
typedef __attribute__((ext_vector_type(4))) float f32x4;

__device__ __forceinline__ unsigned short f2bf(float f) {
  unsigned u = __builtin_bit_cast(unsigned, f);
  unsigned r = (u + 0x7fffu + ((u >> 16) & 1u)) >> 16;   // round-nearest-even
  return (unsigned short)r;
}
__device__ __forceinline__ float bf2f(unsigned short h) {
  unsigned u = ((unsigned)h) << 16;
  return __builtin_bit_cast(float, u);
}

__device__ __forceinline__ void gload_lds16(const unsigned short* g, unsigned short* l) {
  __builtin_amdgcn_global_load_lds(
      (const __attribute__((address_space(1))) unsigned int*)(const void*)g,
      (__attribute__((address_space(3))) unsigned int*)(void*)l, 16, 0, 0);
}

// ---------------------------------------------------------------------------
// bias_pre[h][n][m] = table[relidx[n,m]*12+h]
// ---------------------------------------------------------------------------
__global__ __launch_bounds__(256) void bias_pre_kernel(
    const float* __restrict__ table, const int* __restrict__ relidx,
    float* __restrict__ bias_pre, int total)
{
  int i = blockIdx.x * 256 + threadIdx.x;
  if (i >= total) return;
  int nm = i % (NTOK * NTOK);
  int h  = i / (NTOK * NTOK);
  bias_pre[i] = table[relidx[nm] * NHEAD + h];
}

// ---------------------------------------------------------------------------
// Split fp32 [Mreal x C] into 3 bf16 limb planes [Mpad x C] (pad rows = 0).
// ---------------------------------------------------------------------------
__global__ __launch_bounds__(256) void split3_kernel(
    const float* __restrict__ src,
    unsigned short* __restrict__ d0, unsigned short* __restrict__ d1,
    unsigned short* __restrict__ d2,
    int Mreal, int C, long long total4)
{
  long long idx = (long long)blockIdx.x * 256 + threadIdx.x;
  if (idx >= total4) return;
  long long e = idx * 4;
  int r = (int)(e / C);
  float4 v = make_float4(0.f, 0.f, 0.f, 0.f);
  if (r < Mreal) v = *(const float4*)(src + e);
  const float vv[4] = {v.x, v.y, v.z, v.w};
  ushort4 o0, o1, o2;
  unsigned short* p0 = (unsigned short*)&o0;
  unsigned short* p1 = (unsigned short*)&o1;
  unsigned short* p2 = (unsigned short*)&o2;
#pragma unroll
  for (int i = 0; i < 4; ++i) {
    float x = vv[i];
    unsigned short h0 = f2bf(x);
    float r1 = x - bf2f(h0);
    unsigned short h1 = f2bf(r1);
    float r2 = r1 - bf2f(h1);
    unsigned short h2 = f2bf(r2);
    p0[i] = h0; p1[i] = h1; p2[i] = h2;
  }
  *(ushort4*)(d0 + e) = o0;
  *(ushort4*)(d1 + e) = o1;
  *(ushort4*)(d2 + e) = o2;
}

// ---------------------------------------------------------------------------
// Segment-fused split-bf16 MFMA GEMM (unchanged from round 3).
// ---------------------------------------------------------------------------
template <int NA, int NB, int NSEG, unsigned long long SEGS>
__global__ __launch_bounds__(256, 3) void gemm_fused(
    const unsigned short* __restrict__ A, size_t aplane,
    const unsigned short* __restrict__ B, size_t bplane,
    const float* __restrict__ bias, float* __restrict__ C,
    int M, int N, int K)
{
  __shared__ unsigned short sm[NA + NB][128][32];

  const int nwg = gridDim.x;
  const int orig = blockIdx.x;
  const int q = nwg >> 3, r = nwg & 7;
  const int xcd = orig & 7, pos = orig >> 3;
  const int wg = (xcd < r ? xcd * (q + 1) : r * (q + 1) + (xcd - r) * q) + pos;
  const int gridX = N >> 7;
  const int by = wg / gridX, bx = wg % gridX;
  const int bm = by * 128, bn = bx * 128;

  const int tid = threadIdx.x;
  const int w = tid >> 6, lane = tid & 63;
  const int sr = tid >> 2, gi = tid & 3;
  const int sgW = (gi ^ ((sr >> 1) & 3)) * 8;
  const int scW = gi * 8;
  const int mrow = (w >> 1) * 64 + (lane & 15);
  const int nrow = (w & 1) * 64 + (lane & 15);
  const int kcsw = 8 * ((lane >> 4) ^ (((lane & 15) >> 1) & 3));

  const size_t aoff0 = (size_t)(bm + sr) * K + sgW;
  const size_t aoff1 = (size_t)(bm + sr + 64) * K + sgW;
  const size_t boff0 = (size_t)(bn + sr) * K + sgW;
  const size_t boff1 = (size_t)(bn + sr + 64) * K + sgW;

  f32x4 acc[4][4];
#pragma unroll
  for (int i = 0; i < 4; ++i)
#pragma unroll
    for (int j = 0; j < 4; ++j) acc[i][j] = (f32x4){0.f, 0.f, 0.f, 0.f};

#pragma unroll 1
  for (int k0 = 0; k0 < K; k0 += 32) {
#pragma unroll
    for (int a = 0; a < NA; ++a) {
      const unsigned short* Ap = A + (size_t)a * aplane + k0;
      gload_lds16(Ap + aoff0, &sm[a][sr][scW]);
      gload_lds16(Ap + aoff1, &sm[a][sr + 64][scW]);
    }
#pragma unroll
    for (int b2 = 0; b2 < NB; ++b2) {
      const unsigned short* Bp = B + (size_t)b2 * bplane + k0;
      gload_lds16(Bp + boff0, &sm[NA + b2][sr][scW]);
      gload_lds16(Bp + boff1, &sm[NA + b2][sr + 64][scW]);
    }
    __syncthreads();
#pragma unroll
    for (int s = 0; s < NSEG; ++s) {
      const int ta = (int)((SEGS >> (8 * s)) & 0xFFULL) >> 4;
      const int tb = (int)((SEGS >> (8 * s)) & 0x0FULL);
      short8v av[4], bv[4];
#pragma unroll
      for (int mt = 0; mt < 4; ++mt)
        av[mt] = *(const short8v*)&sm[ta][mrow + mt * 16][kcsw];
#pragma unroll
      for (int nt = 0; nt < 4; ++nt)
        bv[nt] = *(const short8v*)&sm[NA + tb][nrow + nt * 16][kcsw];
#pragma unroll
      for (int mt = 0; mt < 4; ++mt)
#pragma unroll
        for (int nt = 0; nt < 4; ++nt)
          acc[mt][nt] = __builtin_amdgcn_mfma_f32_16x16x32_bf16(
              av[mt], bv[nt], acc[mt][nt], 0, 0, 0);
    }
    __syncthreads();
  }

#pragma unroll
  for (int nt = 0; nt < 4; ++nt) {
    const int col = bn + (w & 1) * 64 + nt * 16 + (lane & 15);
    const float bcol = bias ? bias[col] : 0.0f;
#pragma unroll
    for (int mt = 0; mt < 4; ++mt) {
      const int rowbase = bm + (w >> 1) * 64 + mt * 16 + ((lane >> 4) << 2);
#pragma unroll
      for (int j = 0; j < 4; ++j) {
        const int row = rowbase + j;
        if (row < M) C[(size_t)row * N + col] = acc[mt][nt][j] + bcol;
      }
    }
  }
}

// ---------------------------------------------------------------------------
// Fused binary attention per (b,h), 8 waves. MFMA-based PV.
// Step1: qb/kb sign bits + V -> transposed 2-limb bf16 LDS + scales.
// Step2: 7 groups x 32 rows: popcount logits -> softmax -> z(u8) -> MFMA PV
// (K=6x32 over m=0..191) + VALU correction for m=192..196.
// Output written as 2 bf16 limb planes.
// ---------------------------------------------------------------------------
__global__ __launch_bounds__(512, 4) void attn_kernel(
    const float* __restrict__ qkv, const float* __restrict__ bias_pre,
    unsigned short* __restrict__ att0, unsigned short* __restrict__ att1)
{
  __shared__ unsigned short vT[2][HD][KPV];       // 51,200 B (dequant V^T limbs)
  __shared__ unsigned char  zb[32][KPZ];          //  6,400 B (quantized P rows)
  __shared__ unsigned long long qb[200];          //  1,600 B
  __shared__ unsigned long long kbt[200];         //  1,600 B
  __shared__ float red[16];                       //     64 B  (total 60,864)

  const int bh = blockIdx.x;
  const int b = bh / NHEAD;
  const int h = bh % NHEAD;
  const int tid = threadIdx.x;
  const int w = tid >> 6;
  const int lane = tid & 63;
  const float* base = qkv + (size_t)b * (NTOK * 3 * CDIM) + h * HD;

  // ---- Step 1: sign bits, scales, V quantize -> transposed bf16 limbs ----
  float sq = 0.f, sk = 0.f;
  for (int n = w; n < NTOK; n += 8) {
    const float* row = base + (size_t)n * (3 * CDIM);
    const float qv = row[lane];
    const float kv = row[CDIM + lane];
    const float vv = row[2 * CDIM + lane];
    sq += fabsf(qv);
    sk += fabsf(kv);
    const unsigned long long qm = __ballot(qv >= 0.0f);
    const unsigned long long km = __ballot(kv >= 0.0f);
    if (lane == 0) { qb[n] = qm; kbt[n] = km; }
    const float c = fminf(fmaxf(vv, -2.0f), 2.0f);
    float a = fabsf(c);
#pragma unroll
    for (int off = 32; off; off >>= 1) a = fmaxf(a, __shfl_xor(a, off));
    const float s = 127.0f / (a + 1e-8f);
    const float vq = rintf(c * s) / s;
    const unsigned short l0 = f2bf(vq);
    const unsigned short l1 = f2bf(vq - bf2f(l0));
    vT[0][lane][n] = l0;
    vT[1][lane][n] = l1;
  }
#pragma unroll
  for (int off = 32; off; off >>= 1) {
    sq += __shfl_xor(sq, off);
    sk += __shfl_xor(sk, off);
  }
  if (lane == 0) { red[w] = sq; red[8 + w] = sk; }
  __syncthreads();
  float s_q = 0.f, s_k = 0.f;
#pragma unroll
  for (int i = 0; i < 8; ++i) { s_q += red[i]; s_k += red[8 + i]; }
  s_q *= (1.0f / (NTOK * HD));
  s_k *= (1.0f / (NTOK * HD));
  const float coef = s_q * s_k * 0.125f;  // SCALE = 64^-0.5

  const float* biash = bias_pre + (size_t)h * (NTOK * NTOK);
  const float SP = 1.0f / 255.0f;

  const int mt = w >> 2;                 // M-tile (2)
  const int nt = w & 3;                  // N-tile (4)
  const int arow = mt * 16 + (lane & 15);
  const int bcol = nt * 16 + (lane & 15);
  const int kq8 = 8 * (lane >> 4);
  const int rowb = mt * 16 + ((lane >> 4) << 2);
  const int colOut = h * HD + bcol;

  for (int g = 0; g < 7; ++g) {
    const int r0 = g * 32;

    // ---- softmax + quantize_p: 4 rows per wave ----
#pragma unroll
    for (int i = 0; i < 4; ++i) {
      const int r = r0 + w * 4 + i;
      if (r < NTOK) {
        const unsigned long long qn = qb[r];
        const float* brow = biash + (size_t)r * NTOK;
        float lg[4];
#pragma unroll
        for (int t = 0; t < 4; ++t) {
          const int m = lane + t * 64;
          if (m < NTOK) {
            const int dot = 64 - 2 * __popcll(qn ^ kbt[m]);
            lg[t] = fmaf(coef, (float)dot, brow[m]);
          } else {
            lg[t] = -INFINITY;
          }
        }
        float mx = fmaxf(fmaxf(lg[0], lg[1]), fmaxf(lg[2], lg[3]));
#pragma unroll
        for (int off = 32; off; off >>= 1) mx = fmaxf(mx, __shfl_xor(mx, off));
        const float p0 = expf(lg[0] - mx);
        const float p1 = expf(lg[1] - mx);
        const float p2 = expf(lg[2] - mx);
        const float p3 = expf(lg[3] - mx);
        float sum = p0 + p1 + p2 + p3;
#pragma unroll
        for (int off = 32; off; off >>= 1) sum += __shfl_xor(sum, off);
        float z0 = rintf((p0 / sum) / SP); z0 = fminf(fmaxf(z0, 0.f), 255.f);
        float z1 = rintf((p1 / sum) / SP); z1 = fminf(fmaxf(z1, 0.f), 255.f);
        float z2 = rintf((p2 / sum) / SP); z2 = fminf(fmaxf(z2, 0.f), 255.f);
        float z3 = rintf((p3 / sum) / SP); z3 = fminf(fmaxf(z3, 0.f), 255.f);
        const int zr = w * 4 + i;
        zb[zr][lane]       = (unsigned char)(int)z0;
        zb[zr][lane + 64]  = (unsigned char)(int)z1;
        zb[zr][lane + 128] = (unsigned char)(int)z2;
        if (lane + 192 < NTOK) zb[zr][lane + 192] = (unsigned char)(int)z3;
      }
    }
    __syncthreads();

    // ---- MFMA PV: rows r0+mt*16..+15, cols d = nt*16..+15 ----
    f32x4 acc = (f32x4){0.f, 0.f, 0.f, 0.f};
#pragma unroll
    for (int k0 = 0; k0 < 192; k0 += 32) {
      const unsigned long long a8 =
          *(const unsigned long long*)&zb[arow][k0 + kq8];
      short8v af;
#pragma unroll
      for (int j = 0; j < 8; ++j) {
        const float f = (float)((unsigned)(a8 >> (8 * j)) & 0xFFu);
        af[j] = (short)(__builtin_bit_cast(unsigned, f) >> 16);
      }
      const short8v b0 = *(const short8v*)&vT[0][bcol][k0 + kq8];
      const short8v b1 = *(const short8v*)&vT[1][bcol][k0 + kq8];
      acc = __builtin_amdgcn_mfma_f32_16x16x32_bf16(af, b0, acc, 0, 0, 0);
      acc = __builtin_amdgcn_mfma_f32_16x16x32_bf16(af, b1, acc, 0, 0, 0);
    }
    // ---- tail correction m = 192..196 ----
#pragma unroll
    for (int j = 0; j < 4; ++j) {
      float a = acc[j];
#pragma unroll
      for (int m = 192; m < 197; ++m) {
        const float zv = (float)zb[rowb + j][m];
        const float vv = bf2f(vT[0][bcol][m]) + bf2f(vT[1][bcol][m]);
        a = fmaf(zv, vv, a);
      }
      acc[j] = a;
    }
    // ---- store rows of this group (x SP, split to bf16 limbs) ----
#pragma unroll
    for (int j = 0; j < 4; ++j) {
      const int row = r0 + rowb + j;
      if (row < NTOK) {
        const size_t off = ((size_t)b * NTOK + row) * CDIM + colOut;
        const float o = acc[j] * SP;
        const unsigned short l0 = f2bf(o);
        att0[off] = l0;
        att1[off] = f2bf(o - bf2f(l0));
      }
    }
    __syncthreads();
  }
}

// ---------------------------------------------------------------------------
extern "C" void kernel_launch(void* const* d_in, const int* in_sizes, int n_in,
                              void* d_out, int out_size, void* d_ws, size_t ws_size,
                              hipStream_t stream)
{
  (void)in_sizes; (void)n_in; (void)out_size;
  const float* x      = (const float*)d_in[0];
  const float* qkv_w  = (const float*)d_in[1];
  const float* proj_w = (const float*)d_in[2];
  const float* proj_b = (const float*)d_in[3];
  const float* table  = (const float*)d_in[4];
  const int*   relidx = (const int*)d_in[5];
  float* out = (float*)d_out;

  const size_t biasElems = (size_t)NHEAD * NTOK * NTOK;       // 465708 f32
  const size_t wqPlane = (size_t)(3 * CDIM) * CDIM;           // 2304*768 bf16
  const size_t wpPlane = (size_t)CDIM * CDIM;                 // 768*768  bf16

  // adaptive batch chunk
  int nb = 128;
  size_t Mpad = 0;
  for (;; nb >>= 1) {
    size_t Mreal = (size_t)nb * NTOK;
    Mpad = (Mreal + 127) & ~(size_t)127;
    size_t need = biasElems * 4 + (3 * wqPlane + 3 * wpPlane) * 2 +
                  3 * Mpad * CDIM * 2 +          // x/att split planes (bf16)
                  Mpad * (size_t)(3 * CDIM) * 4; // qkv buf (f32)
    if (need <= ws_size || nb == 1) break;
  }

  char* p = (char*)d_ws;
  float* bias_pre = (float*)p;               p += biasElems * 4;
  unsigned short* wq = (unsigned short*)p;   p += 3 * wqPlane * 2;
  unsigned short* wp = (unsigned short*)p;   p += 3 * wpPlane * 2;
  unsigned short* xs = (unsigned short*)p;   p += 3 * Mpad * CDIM * 2;
  float* qkvbuf = (float*)p;

  const size_t xPlane = Mpad * CDIM;

  {
    const int total = (int)biasElems;
    bias_pre_kernel<<<(total + 255) / 256, 256, 0, stream>>>(table, relidx, bias_pre, total);
  }
  {
    long long t4 = (long long)(3 * CDIM) * CDIM / 4;
    split3_kernel<<<(int)((t4 + 255) / 256), 256, 0, stream>>>(
        qkv_w, wq, wq + wqPlane, wq + 2 * wqPlane, 3 * CDIM, CDIM, t4);
    t4 = (long long)CDIM * CDIM / 4;
    split3_kernel<<<(int)((t4 + 255) / 256), 256, 0, stream>>>(
        proj_w, wp, wp + wpPlane, wp + 2 * wpPlane, CDIM, CDIM, t4);
  }

  constexpr unsigned long long SEG_QKV = 0x201110020100ULL;  // {00,01,02,10,11,20}
  constexpr unsigned long long SEG_PRJ = 0x100100ULL;        // {00,01,10}

  for (int b0 = 0; b0 < 128; b0 += nb) {
    const int curB = (128 - b0 < nb) ? (128 - b0) : nb;
    const int Mreal = curB * NTOK;
    {
      long long t4 = (long long)Mpad * CDIM / 4;
      split3_kernel<<<(int)((t4 + 255) / 256), 256, 0, stream>>>(
          x + (size_t)b0 * NTOK * CDIM, xs, xs + xPlane, xs + 2 * xPlane,
          Mreal, CDIM, t4);
    }
    gemm_fused<3, 3, 6, SEG_QKV>
        <<<(int)(Mpad / 128) * ((3 * CDIM) / 128), 256, 0, stream>>>(
        xs, xPlane, wq, wqPlane, nullptr, qkvbuf, Mreal, 3 * CDIM, CDIM);
    attn_kernel<<<curB * NHEAD, 512, 0, stream>>>(qkvbuf, bias_pre, xs, xs + xPlane);
    gemm_fused<2, 2, 3, SEG_PRJ>
        <<<(int)(Mpad / 128) * (CDIM / 128), 256, 0, stream>>>(
        xs, xPlane, wp, wpPlane, proj_b, out + (size_t)b0 * NTOK * CDIM,
        Mreal, CDIM, CDIM);
  }
}

// Round 5
// 1024.240 us; speedup vs baseline: 2.2586x; 1.1326x over previous
//
#include <hip/hip_runtime.h>
#include <cstdint>
#include <cmath>

#define NTOK 197
#define NHEAD 12
#define HD 64
#define CDIM 768
#define KPZ 200   // z-row stride (bytes, mult of 8)
#define KPV 200   // vT-row stride (shorts, mult of 8)

typedef __attribute__((ext_vector_type(8))) short short8v;   // 8 bf16
typedef __attribute__((ext_vector_type(4))) float f32x4;

__device__ __forceinline__ unsigned short f2bf(float f) {
  unsigned u = __builtin_bit_cast(unsigned, f);
  unsigned r = (u + 0x7fffu + ((u >> 16) & 1u)) >> 16;   // round-nearest-even
  return (unsigned short)r;
}
__device__ __forceinline__ float bf2f(unsigned short h) {
  unsigned u = ((unsigned)h) << 16;
  return __builtin_bit_cast(float, u);
}

__device__ __forceinline__ void gload_lds16(const unsigned short* g, unsigned short* l) {
  __builtin_amdgcn_global_load_lds(
      (const __attribute__((address_space(1))) unsigned int*)(const void*)g,
      (__attribute__((address_space(3))) unsigned int*)(void*)l, 16, 0, 0);
}

// ---------------------------------------------------------------------------
// bias_pre[h][n][m] = table[relidx[n,m]*12+h]
// ---------------------------------------------------------------------------
__global__ __launch_bounds__(256) void bias_pre_kernel(
    const float* __restrict__ table, const int* __restrict__ relidx,
    float* __restrict__ bias_pre, int total)
{
  int i = blockIdx.x * 256 + threadIdx.x;
  if (i >= total) return;
  int nm = i % (NTOK * NTOK);
  int h  = i / (NTOK * NTOK);
  bias_pre[i] = table[relidx[nm] * NHEAD + h];
}

// ---------------------------------------------------------------------------
// Split fp32 [Mreal x C] into 3 bf16 limb planes [Mpad x C] (pad rows = 0).
// ---------------------------------------------------------------------------
__global__ __launch_bounds__(256) void split3_kernel(
    const float* __restrict__ src,
    unsigned short* __restrict__ d0, unsigned short* __restrict__ d1,
    unsigned short* __restrict__ d2,
    int Mreal, int C, long long total4)
{
  long long idx = (long long)blockIdx.x * 256 + threadIdx.x;
  if (idx >= total4) return;
  long long e = idx * 4;
  int r = (int)(e / C);
  float4 v = make_float4(0.f, 0.f, 0.f, 0.f);
  if (r < Mreal) v = *(const float4*)(src + e);
  const float vv[4] = {v.x, v.y, v.z, v.w};
  ushort4 o0, o1, o2;
  unsigned short* p0 = (unsigned short*)&o0;
  unsigned short* p1 = (unsigned short*)&o1;
  unsigned short* p2 = (unsigned short*)&o2;
#pragma unroll
  for (int i = 0; i < 4; ++i) {
    float x = vv[i];
    unsigned short h0 = f2bf(x);
    float r1 = x - bf2f(h0);
    unsigned short h1 = f2bf(r1);
    float r2 = r1 - bf2f(h1);
    unsigned short h2 = f2bf(r2);
    p0[i] = h0; p1[i] = h1; p2[i] = h2;
  }
  *(ushort4*)(d0 + e) = o0;
  *(ushort4*)(d1 + e) = o1;
  *(ushort4*)(d2 + e) = o2;
}

// ---------------------------------------------------------------------------
// Segment-fused split-bf16 MFMA GEMM.
// Segments: A-limb ta paired with B-limbs tb < CNT[ta] (A-major order).
// Per K-step: stage NA+NB limb tiles once; cache ALL B fragments in VGPRs
// (one ds_read set per plane), load A fragments once per ta -> 24 ds_reads
// per 96 MFMAs (qkv) instead of 48.
// Block schedule: XCD-chunk swizzle + banded decode (TN=6 bx-columns per
// band, by fastest inside) so each XCD keeps a 3.5 MB B-slice L2-resident
// while streaming A.
// ---------------------------------------------------------------------------
template <int NA, int NB, int C0, int C1, int C2>
__global__ __launch_bounds__(256, 3) void gemm_fused(
    const unsigned short* __restrict__ A, size_t aplane,
    const unsigned short* __restrict__ B, size_t bplane,
    const float* __restrict__ bias, float* __restrict__ C,
    int M, int N, int K)
{
  __shared__ unsigned short sm[NA + NB][128][32];

  // bijective XCD-chunk block swizzle (m204)
  const int nwg = gridDim.x;
  const int orig = blockIdx.x;
  const int q = nwg >> 3, r = nwg & 7;
  const int xcd = orig & 7, pos = orig >> 3;
  const int wg = (xcd < r ? xcd * (q + 1) : r * (q + 1) + (xcd - r) * q) + pos;
  // banded decode: bands of 6 bx-columns, by fastest within band
  const int gridX = N >> 7;
  const int gridY = wg / 0;  // placeholder (overwritten below; avoids unused warn)
  (void)gridY;
  const int bandSz = (M + 127) / 128 * 6;
  const int band = wg / bandSz;
  const int rem = wg % bandSz;
  const int by = rem / 6;
  const int bx = band * 6 + rem % 6;
  (void)gridX;
  const int bm = by * 128, bn = bx * 128;

  const int tid = threadIdx.x;
  const int w = tid >> 6, lane = tid & 63;
  const int sr = tid >> 2, gi = tid & 3;
  const int sgW = (gi ^ ((sr >> 1) & 3)) * 8;     // swizzled source col (shorts)
  const int scW = gi * 8;                         // linear LDS dest col
  const int mrow = (w >> 1) * 64 + (lane & 15);
  const int nrow = (w & 1) * 64 + (lane & 15);
  const int kcsw = 8 * ((lane >> 4) ^ (((lane & 15) >> 1) & 3));

  const size_t aoff0 = (size_t)(bm + sr) * K + sgW;
  const size_t aoff1 = (size_t)(bm + sr + 64) * K + sgW;
  const size_t boff0 = (size_t)(bn + sr) * K + sgW;
  const size_t boff1 = (size_t)(bn + sr + 64) * K + sgW;

  f32x4 acc[4][4];
#pragma unroll
  for (int i = 0; i < 4; ++i)
#pragma unroll
    for (int j = 0; j < 4; ++j) acc[i][j] = (f32x4){0.f, 0.f, 0.f, 0.f};

#pragma unroll 1
  for (int k0 = 0; k0 < K; k0 += 32) {
#pragma unroll
    for (int a = 0; a < NA; ++a) {
      const unsigned short* Ap = A + (size_t)a * aplane + k0;
      gload_lds16(Ap + aoff0, &sm[a][sr][scW]);
      gload_lds16(Ap + aoff1, &sm[a][sr + 64][scW]);
    }
#pragma unroll
    for (int b2 = 0; b2 < NB; ++b2) {
      const unsigned short* Bp = B + (size_t)b2 * bplane + k0;
      gload_lds16(Bp + boff0, &sm[NA + b2][sr][scW]);
      gload_lds16(Bp + boff1, &sm[NA + b2][sr + 64][scW]);
    }
    __syncthreads();

    // cache ALL B fragments (one read set per plane)
    short8v bv[NB][4];
#pragma unroll
    for (int b2 = 0; b2 < NB; ++b2)
#pragma unroll
      for (int nt = 0; nt < 4; ++nt)
        bv[b2][nt] = *(const short8v*)&sm[NA + b2][nrow + nt * 16][kcsw];

#pragma unroll
    for (int ta = 0; ta < NA; ++ta) {
      const int cnt = (ta == 0) ? C0 : (ta == 1 ? C1 : C2);
      if (cnt == 0) continue;
      short8v av[4];
#pragma unroll
      for (int mt = 0; mt < 4; ++mt)
        av[mt] = *(const short8v*)&sm[ta][mrow + mt * 16][kcsw];
#pragma unroll
      for (int tb = 0; tb < NB; ++tb) {
        if (tb < cnt) {
#pragma unroll
          for (int mt = 0; mt < 4; ++mt)
#pragma unroll
            for (int nt = 0; nt < 4; ++nt)
              acc[mt][nt] = __builtin_amdgcn_mfma_f32_16x16x32_bf16(
                  av[mt], bv[tb][nt], acc[mt][nt], 0, 0, 0);
        }
      }
    }
    __syncthreads();
  }

  // epilogue: C/D layout col = lane&15, row = (lane>>4)*4 + j
#pragma unroll
  for (int nt = 0; nt < 4; ++nt) {
    const int col = bn + (w & 1) * 64 + nt * 16 + (lane & 15);
    const float bcol = bias ? bias[col] : 0.0f;
#pragma unroll
    for (int mt = 0; mt < 4; ++mt) {
      const int rowbase = bm + (w >> 1) * 64 + mt * 16 + ((lane >> 4) << 2);
#pragma unroll
      for (int j = 0; j < 4; ++j) {
        const int row = rowbase + j;
        if (row < M) C[(size_t)row * N + col] = acc[mt][nt][j] + bcol;
      }
    }
  }
}

// ---------------------------------------------------------------------------
// Fused binary attention per (b,h), 8 waves, MFMA PV (unchanged from r4).
// ---------------------------------------------------------------------------
__global__ __launch_bounds__(512, 4) void attn_kernel(
    const float* __restrict__ qkv, const float* __restrict__ bias_pre,
    unsigned short* __restrict__ att0, unsigned short* __restrict__ att1)
{
  __shared__ unsigned short vT[2][HD][KPV];
  __shared__ unsigned char  zb[32][KPZ];
  __shared__ unsigned long long qb[200];
  __shared__ unsigned long long kbt[200];
  __shared__ float red[16];

  const int bh = blockIdx.x;
  const int b = bh / NHEAD;
  const int h = bh % NHEAD;
  const int tid = threadIdx.x;
  const int w = tid >> 6;
  const int lane = tid & 63;
  const float* base = qkv + (size_t)b * (NTOK * 3 * CDIM) + h * HD;

  float sq = 0.f, sk = 0.f;
  for (int n = w; n < NTOK; n += 8) {
    const float* row = base + (size_t)n * (3 * CDIM);
    const float qv = row[lane];
    const float kv = row[CDIM + lane];
    const float vv = row[2 * CDIM + lane];
    sq += fabsf(qv);
    sk += fabsf(kv);
    const unsigned long long qm = __ballot(qv >= 0.0f);
    const unsigned long long km = __ballot(kv >= 0.0f);
    if (lane == 0) { qb[n] = qm; kbt[n] = km; }
    const float c = fminf(fmaxf(vv, -2.0f), 2.0f);
    float a = fabsf(c);
#pragma unroll
    for (int off = 32; off; off >>= 1) a = fmaxf(a, __shfl_xor(a, off));
    const float s = 127.0f / (a + 1e-8f);
    const float vq = rintf(c * s) / s;
    const unsigned short l0 = f2bf(vq);
    const unsigned short l1 = f2bf(vq - bf2f(l0));
    vT[0][lane][n] = l0;
    vT[1][lane][n] = l1;
  }
#pragma unroll
  for (int off = 32; off; off >>= 1) {
    sq += __shfl_xor(sq, off);
    sk += __shfl_xor(sk, off);
  }
  if (lane == 0) { red[w] = sq; red[8 + w] = sk; }
  __syncthreads();
  float s_q = 0.f, s_k = 0.f;
#pragma unroll
  for (int i = 0; i < 8; ++i) { s_q += red[i]; s_k += red[8 + i]; }
  s_q *= (1.0f / (NTOK * HD));
  s_k *= (1.0f / (NTOK * HD));
  const float coef = s_q * s_k * 0.125f;

  const float* biash = bias_pre + (size_t)h * (NTOK * NTOK);
  const float SP = 1.0f / 255.0f;

  const int mt = w >> 2;
  const int nt = w & 3;
  const int arow = mt * 16 + (lane & 15);
  const int bcol = nt * 16 + (lane & 15);
  const int kq8 = 8 * (lane >> 4);
  const int rowb = mt * 16 + ((lane >> 4) << 2);
  const int colOut = h * HD + bcol;

  for (int g = 0; g < 7; ++g) {
    const int r0 = g * 32;

#pragma unroll
    for (int i = 0; i < 4; ++i) {
      const int r = r0 + w * 4 + i;
      if (r < NTOK) {
        const unsigned long long qn = qb[r];
        const float* brow = biash + (size_t)r * NTOK;
        float lg[4];
#pragma unroll
        for (int t = 0; t < 4; ++t) {
          const int m = lane + t * 64;
          if (m < NTOK) {
            const int dot = 64 - 2 * __popcll(qn ^ kbt[m]);
            lg[t] = fmaf(coef, (float)dot, brow[m]);
          } else {
            lg[t] = -INFINITY;
          }
        }
        float mx = fmaxf(fmaxf(lg[0], lg[1]), fmaxf(lg[2], lg[3]));
#pragma unroll
        for (int off = 32; off; off >>= 1) mx = fmaxf(mx, __shfl_xor(mx, off));
        const float p0 = expf(lg[0] - mx);
        const float p1 = expf(lg[1] - mx);
        const float p2 = expf(lg[2] - mx);
        const float p3 = expf(lg[3] - mx);
        float sum = p0 + p1 + p2 + p3;
#pragma unroll
        for (int off = 32; off; off >>= 1) sum += __shfl_xor(sum, off);
        float z0 = rintf((p0 / sum) / SP); z0 = fminf(fmaxf(z0, 0.f), 255.f);
        float z1 = rintf((p1 / sum) / SP); z1 = fminf(fmaxf(z1, 0.f), 255.f);
        float z2 = rintf((p2 / sum) / SP); z2 = fminf(fmaxf(z2, 0.f), 255.f);
        float z3 = rintf((p3 / sum) / SP); z3 = fminf(fmaxf(z3, 0.f), 255.f);
        const int zr = w * 4 + i;
        zb[zr][lane]       = (unsigned char)(int)z0;
        zb[zr][lane + 64]  = (unsigned char)(int)z1;
        zb[zr][lane + 128] = (unsigned char)(int)z2;
        if (lane + 192 < NTOK) zb[zr][lane + 192] = (unsigned char)(int)z3;
      }
    }
    __syncthreads();

    f32x4 acc = (f32x4){0.f, 0.f, 0.f, 0.f};
#pragma unroll
    for (int k0 = 0; k0 < 192; k0 += 32) {
      const unsigned long long a8 =
          *(const unsigned long long*)&zb[arow][k0 + kq8];
      short8v af;
#pragma unroll
      for (int j = 0; j < 8; ++j) {
        const float f = (float)((unsigned)(a8 >> (8 * j)) & 0xFFu);
        af[j] = (short)(__builtin_bit_cast(unsigned, f) >> 16);
      }
      const short8v b0 = *(const short8v*)&vT[0][bcol][k0 + kq8];
      const short8v b1 = *(const short8v*)&vT[1][bcol][k0 + kq8];
      acc = __builtin_amdgcn_mfma_f32_16x16x32_bf16(af, b0, acc, 0, 0, 0);
      acc = __builtin_amdgcn_mfma_f32_16x16x32_bf16(af, b1, acc, 0, 0, 0);
    }
#pragma unroll
    for (int j = 0; j < 4; ++j) {
      float a = acc[j];
#pragma unroll
      for (int m = 192; m < 197; ++m) {
        const float zv = (float)zb[rowb + j][m];
        const float vv = bf2f(vT[0][bcol][m]) + bf2f(vT[1][bcol][m]);
        a = fmaf(zv, vv, a);
      }
      acc[j] = a;
    }
#pragma unroll
    for (int j = 0; j < 4; ++j) {
      const int row = r0 + rowb + j;
      if (row < NTOK) {
        const size_t off = ((size_t)b * NTOK + row) * CDIM + colOut;
        const float o = acc[j] * SP;
        const unsigned short l0 = f2bf(o);
        att0[off] = l0;
        att1[off] = f2bf(o - bf2f(l0));
      }
    }
    __syncthreads();
  }
}

// ---------------------------------------------------------------------------
extern "C" void kernel_launch(void* const* d_in, const int* in_sizes, int n_in,
                              void* d_out, int out_size, void* d_ws, size_t ws_size,
                              hipStream_t stream)
{
  (void)in_sizes; (void)n_in; (void)out_size;
  const float* x      = (const float*)d_in[0];
  const float* qkv_w  = (const float*)d_in[1];
  const float* proj_w = (const float*)d_in[2];
  const float* proj_b = (const float*)d_in[3];
  const float* table  = (const float*)d_in[4];
  const int*   relidx = (const int*)d_in[5];
  float* out = (float*)d_out;

  const size_t biasElems = (size_t)NHEAD * NTOK * NTOK;
  const size_t wqPlane = (size_t)(3 * CDIM) * CDIM;
  const size_t wpPlane = (size_t)CDIM * CDIM;

  int nb = 128;
  size_t Mpad = 0;
  for (;; nb >>= 1) {
    size_t Mreal = (size_t)nb * NTOK;
    Mpad = (Mreal + 127) & ~(size_t)127;
    size_t need = biasElems * 4 + (3 * wqPlane + 3 * wpPlane) * 2 +
                  3 * Mpad * CDIM * 2 +
                  Mpad * (size_t)(3 * CDIM) * 4;
    if (need <= ws_size || nb == 1) break;
  }

  char* p = (char*)d_ws;
  float* bias_pre = (float*)p;               p += biasElems * 4;
  unsigned short* wq = (unsigned short*)p;   p += 3 * wqPlane * 2;
  unsigned short* wp = (unsigned short*)p;   p += 3 * wpPlane * 2;
  unsigned short* xs = (unsigned short*)p;   p += 3 * Mpad * CDIM * 2;
  float* qkvbuf = (float*)p;

  const size_t xPlane = Mpad * CDIM;

  {
    const int total = (int)biasElems;
    bias_pre_kernel<<<(total + 255) / 256, 256, 0, stream>>>(table, relidx, bias_pre, total);
  }
  {
    long long t4 = (long long)(3 * CDIM) * CDIM / 4;
    split3_kernel<<<(int)((t4 + 255) / 256), 256, 0, stream>>>(
        qkv_w, wq, wq + wqPlane, wq + 2 * wqPlane, 3 * CDIM, CDIM, t4);
    t4 = (long long)CDIM * CDIM / 4;
    split3_kernel<<<(int)((t4 + 255) / 256), 256, 0, stream>>>(
        proj_w, wp, wp + wpPlane, wp + 2 * wpPlane, CDIM, CDIM, t4);
  }

  for (int b0 = 0; b0 < 128; b0 += nb) {
    const int curB = (128 - b0 < nb) ? (128 - b0) : nb;
    const int Mreal = curB * NTOK;
    {
      long long t4 = (long long)Mpad * CDIM / 4;
      split3_kernel<<<(int)((t4 + 255) / 256), 256, 0, stream>>>(
          x + (size_t)b0 * NTOK * CDIM, xs, xs + xPlane, xs + 2 * xPlane,
          Mreal, CDIM, t4);
    }
    // qkv: segments {00,01,02},{10,11},{20}
    gemm_fused<3, 3, 3, 2, 1>
        <<<(int)(Mpad / 128) * ((3 * CDIM) / 128), 256, 0, stream>>>(
        xs, xPlane, wq, wqPlane, nullptr, qkvbuf, Mreal, 3 * CDIM, CDIM);
    attn_kernel<<<curB * NHEAD, 512, 0, stream>>>(qkvbuf, bias_pre, xs, xs + xPlane);
    // proj: segments {00,01},{10}
    gemm_fused<2, 2, 2, 1, 0>
        <<<(int)(Mpad / 128) * (CDIM / 128), 256, 0, stream>>>(
        xs, xPlane, wp, wpPlane, proj_b, out + (size_t)b0 * NTOK * CDIM,
        Mreal, CDIM, CDIM);
  }
}